// Round 2
// baseline (747.002 us; speedup 1.0000x reference)
//
#include <hip/hip_runtime.h>

typedef _Float16 half8 __attribute__((ext_vector_type(8)));
typedef float floatx4 __attribute__((ext_vector_type(4)));

// global -> LDS async copy, 16B per lane.
__device__ __forceinline__ void g2lds16(const void* g, void* l) {
    __builtin_amdgcn_global_load_lds(
        (const __attribute__((address_space(1))) void*)(unsigned long long)g,
        (__attribute__((address_space(3))) void*)(unsigned int)(unsigned long long)l,
        16, 0, 0);
}

// ---------------- CSR build: direct node-level counting sort ----------------
// SpMM only needs edges grouped by dst (within-node order is free: summation
// order was already nondeterministic in the bucket-sort version and passes).

// fused: weight prep (blocks 0..287) + degree count (blocks 288+)
__global__ __launch_bounds__(256) void k_prep_count(const float* __restrict__ W1,
                                                    const float* __restrict__ W2,
                                                    _Float16* __restrict__ w1hi,
                                                    _Float16* __restrict__ w1lo,
                                                    _Float16* __restrict__ w2hi,
                                                    _Float16* __restrict__ w2lo,
                                                    const int* __restrict__ dst,
                                                    int* __restrict__ deg, int E) {
    int b = blockIdx.x;
    int t = threadIdx.x;
    if (b < 256) {            // prep W1: fp32 -> fp16 hi/lo, transposed [n][k]
        int tid = b * 256 + t;            // 65536 = 128*512
        int n = tid >> 9;
        int k = tid & 511;
        float w = W1[(size_t)k * 128 + n];
        _Float16 h = (_Float16)w;
        w1hi[tid] = h;
        w1lo[tid] = (_Float16)(w - (float)h);
        return;
    }
    if (b < 288) {            // prep W2
        int tid = (b - 256) * 256 + t;    // 8192 = 64*128
        int n = tid >> 7;
        int k = tid & 127;
        float w = W2[(size_t)k * 64 + n];
        _Float16 h = (_Float16)w;
        w2hi[tid] = h;
        w2lo[tid] = (_Float16)(w - (float)h);
        return;
    }
    int i0 = ((b - 288) * 256 + t) * 4;
    if (i0 + 3 < E) {
        int4 d4 = *(const int4*)(dst + i0);
        atomicAdd(&deg[d4.x], 1);
        atomicAdd(&deg[d4.y], 1);
        atomicAdd(&deg[d4.z], 1);
        atomicAdd(&deg[d4.w], 1);
    } else {
        for (int i = i0; i < E; ++i)
            atomicAdd(&deg[dst[i]], 1);
    }
}

// scan phase A: per-chunk (1024) exclusive scan + chunk totals
__global__ __launch_bounds__(1024) void k_scan_a(const int* __restrict__ deg,
                                                 int* __restrict__ rowptr,
                                                 int* __restrict__ partial, int M) {
    __shared__ int s[1024];
    int c = blockIdx.x, t = threadIdx.x;
    int i = c * 1024 + t;
    int v = (i < M) ? deg[i] : 0;
    s[t] = v;
    __syncthreads();
    for (int off = 1; off < 1024; off <<= 1) {
        int u = (t >= off) ? s[t - off] : 0;
        __syncthreads();
        s[t] += u;
        __syncthreads();
    }
    if (i < M) rowptr[i] = s[t] - v;      // exclusive within chunk
    if (t == 1023) partial[c] = s[t];     // chunk total
}

// scan phase B: add chunk-prefix, emit final rowptr + cursor copy
__global__ __launch_bounds__(1024) void k_scan_b(const int* __restrict__ partial,
                                                 int* __restrict__ rowptr,
                                                 int* __restrict__ cur,
                                                 int M, int E, int NCH) {
    __shared__ int sp[128];               // NCH <= 128 (M <= 131072)
    int c = blockIdx.x, t = threadIdx.x;
    if (t < NCH) sp[t] = partial[t];
    __syncthreads();
    int pre = 0;
    for (int j = 0; j < c; ++j) pre += sp[j];
    int i = c * 1024 + t;
    if (i < M) {
        int r = rowptr[i] + pre;
        rowptr[i] = r;
        cur[i] = r;
    }
    if (c == NCH - 1 && t == 1023) rowptr[M] = E;
}

// direct scatter into node-grouped edge array
__global__ __launch_bounds__(256) void k_scatter(const int* __restrict__ src,
                                                 const int* __restrict__ dst,
                                                 const float* __restrict__ val,
                                                 int* __restrict__ cur,
                                                 int2* __restrict__ ssv, int E) {
    int i0 = (blockIdx.x * 256 + threadIdx.x) * 4;
    if (i0 + 3 < E) {
        int4 s4 = *(const int4*)(src + i0);
        int4 d4 = *(const int4*)(dst + i0);
        float4 v4 = *(const float4*)(val + i0);
        int p;
        p = atomicAdd(&cur[d4.x], 1); ssv[p] = make_int2(s4.x, __float_as_int(v4.x));
        p = atomicAdd(&cur[d4.y], 1); ssv[p] = make_int2(s4.y, __float_as_int(v4.y));
        p = atomicAdd(&cur[d4.z], 1); ssv[p] = make_int2(s4.z, __float_as_int(v4.z));
        p = atomicAdd(&cur[d4.w], 1); ssv[p] = make_int2(s4.w, __float_as_int(v4.w));
    } else {
        for (int i = i0; i < E; ++i) {
            int p = atomicAdd(&cur[dst[i]], 1);
            ssv[p] = make_int2(src[i], __float_as_int(val[i]));
        }
    }
}

// ---------------- split helper ----------------

__device__ __forceinline__ void split8(float4 f0, float4 f1, half8& h, half8& l) {
    float f[8] = {f0.x, f0.y, f0.z, f0.w, f1.x, f1.y, f1.z, f1.w};
#pragma unroll
    for (int j = 0; j < 8; ++j) {
        _Float16 hi = (_Float16)f[j];
        h[j] = hi;
        l[j] = (_Float16)(f[j] - (float)hi);
    }
}

// ---------------- GEMM1: [M,512]@[512,128]+b1, split-fp16 MFMA ----------------

__global__ __launch_bounds__(256) void gemm1_mfma(const float* __restrict__ X,
                                                  const _Float16* __restrict__ Whi,
                                                  const _Float16* __restrict__ Wlo,
                                                  const float* __restrict__ bias,
                                                  float* __restrict__ out, int M) {
    __shared__ char smem[2 * 16384];
    int t = threadIdx.x;
    int w = t >> 6;
    int lane = t & 63;
    int quad = lane >> 4;
    int l16 = lane & 15;
    int bm = blockIdx.x * 128;
    int m0 = bm + w * 32;

    int ra0 = min(m0 + l16, M - 1);
    int ra1 = min(m0 + 16 + l16, M - 1);
    const float* a0p = X + (size_t)ra0 * 512 + quad * 8;
    const float* a1p = X + (size_t)ra1 * 512 + quad * 8;

    int chunk0 = w * 4;
    const _Float16* gsrc[4];
#pragma unroll
    for (int c = 0; c < 4; ++c) {
        int idx = (chunk0 + c) * 1024 + lane * 16;
        int sec = idx >> 13;
        int row = (idx & 8191) >> 6;
        int kch = (idx >> 4) & 3;
        gsrc[c] = (sec ? Wlo : Whi) + (size_t)row * 512 + kch * 8;
    }
#pragma unroll
    for (int c = 0; c < 4; ++c)
        g2lds16(gsrc[c], smem + (chunk0 + c) * 1024);
    float4 af00 = *(const float4*)(a0p);
    float4 af01 = *(const float4*)(a0p + 4);
    float4 af10 = *(const float4*)(a1p);
    float4 af11 = *(const float4*)(a1p + 4);

    floatx4 acc[2][8];
#pragma unroll
    for (int mt = 0; mt < 2; ++mt)
#pragma unroll
        for (int nt = 0; nt < 8; ++nt) acc[mt][nt] = (floatx4){0.f, 0.f, 0.f, 0.f};

    for (int i = 0; i < 16; ++i) {
        int k0 = i * 32;
        __syncthreads();
        if (i < 15) {
            char* nbuf = smem + ((i + 1) & 1) * 16384;
#pragma unroll
            for (int c = 0; c < 4; ++c)
                g2lds16(gsrc[c] + k0 + 32, nbuf + (chunk0 + c) * 1024);
        }
        float4 nf00 = af00, nf01 = af01, nf10 = af10, nf11 = af11;
        if (i < 15) {
            nf00 = *(const float4*)(a0p + k0 + 32);
            nf01 = *(const float4*)(a0p + k0 + 36);
            nf10 = *(const float4*)(a1p + k0 + 32);
            nf11 = *(const float4*)(a1p + k0 + 36);
        }
        const char* buf = smem + (i & 1) * 16384;
        half8 bh[8], bl[8];
#pragma unroll
        for (int nt = 0; nt < 8; ++nt) {
            int off = (nt * 16 + l16) * 64 + quad * 16;
            bh[nt] = *(const half8*)(buf + off);
            bl[nt] = *(const half8*)(buf + 8192 + off);
        }
        half8 ah0, al0, ah1, al1;
        split8(af00, af01, ah0, al0);
        split8(af10, af11, ah1, al1);
#pragma unroll
        for (int nt = 0; nt < 8; ++nt) {
            acc[0][nt] = __builtin_amdgcn_mfma_f32_16x16x32_f16(ah0, bh[nt], acc[0][nt], 0, 0, 0);
            acc[1][nt] = __builtin_amdgcn_mfma_f32_16x16x32_f16(ah1, bh[nt], acc[1][nt], 0, 0, 0);
            acc[0][nt] = __builtin_amdgcn_mfma_f32_16x16x32_f16(ah0, bl[nt], acc[0][nt], 0, 0, 0);
            acc[1][nt] = __builtin_amdgcn_mfma_f32_16x16x32_f16(ah1, bl[nt], acc[1][nt], 0, 0, 0);
            acc[0][nt] = __builtin_amdgcn_mfma_f32_16x16x32_f16(al0, bh[nt], acc[0][nt], 0, 0, 0);
            acc[1][nt] = __builtin_amdgcn_mfma_f32_16x16x32_f16(al1, bh[nt], acc[1][nt], 0, 0, 0);
        }
        af00 = nf00; af01 = nf01; af10 = nf10; af11 = nf11;
    }

#pragma unroll
    for (int nt = 0; nt < 8; ++nt) {
        int col = nt * 16 + l16;
        float bv = bias[col];
#pragma unroll
        for (int mt = 0; mt < 2; ++mt)
#pragma unroll
            for (int r = 0; r < 4; ++r) {
                int row = m0 + mt * 16 + quad * 4 + r;
                if (row < M) out[(size_t)row * 128 + col] = acc[mt][nt][r] + bv;
            }
    }
}

// ---------------- GEMM2: relu([M,128])@[128,64]+b2, split-fp16 MFMA ----------------

__global__ __launch_bounds__(256) void gemm2_mfma(const float* __restrict__ H,
                                                  const _Float16* __restrict__ Whi,
                                                  const _Float16* __restrict__ Wlo,
                                                  const float* __restrict__ bias,
                                                  float* __restrict__ out, int M) {
    __shared__ char smem[2 * 64 * 320];
    int t = threadIdx.x;
#pragma unroll
    for (int i = 0; i < 4; ++i) {
        int gidx = i * 256 + t;
        int row = gidx >> 4, col = gidx & 15;
        *(float4*)(smem + row * 320 + col * 16) = ((const float4*)Whi)[gidx];
        *(float4*)(smem + 20480 + row * 320 + col * 16) = ((const float4*)Wlo)[gidx];
    }
    __syncthreads();

    int w = t >> 6;
    int lane = t & 63;
    int quad = lane >> 4;
    int l16 = lane & 15;
    int m0 = blockIdx.x * 128 + w * 32;
    int ra0 = min(m0 + l16, M - 1);
    int ra1 = min(m0 + 16 + l16, M - 1);
    const float* a0p = H + (size_t)ra0 * 128 + quad * 8;
    const float* a1p = H + (size_t)ra1 * 128 + quad * 8;

    floatx4 acc[2][4];
#pragma unroll
    for (int mt = 0; mt < 2; ++mt)
#pragma unroll
        for (int nt = 0; nt < 4; ++nt) acc[mt][nt] = (floatx4){0.f, 0.f, 0.f, 0.f};

#pragma unroll
    for (int k0 = 0; k0 < 128; k0 += 32) {
        float4 af00 = *(const float4*)(a0p + k0);
        float4 af01 = *(const float4*)(a0p + k0 + 4);
        float4 af10 = *(const float4*)(a1p + k0);
        float4 af11 = *(const float4*)(a1p + k0 + 4);
        af00.x = fmaxf(af00.x, 0.f); af00.y = fmaxf(af00.y, 0.f);
        af00.z = fmaxf(af00.z, 0.f); af00.w = fmaxf(af00.w, 0.f);
        af01.x = fmaxf(af01.x, 0.f); af01.y = fmaxf(af01.y, 0.f);
        af01.z = fmaxf(af01.z, 0.f); af01.w = fmaxf(af01.w, 0.f);
        af10.x = fmaxf(af10.x, 0.f); af10.y = fmaxf(af10.y, 0.f);
        af10.z = fmaxf(af10.z, 0.f); af10.w = fmaxf(af10.w, 0.f);
        af11.x = fmaxf(af11.x, 0.f); af11.y = fmaxf(af11.y, 0.f);
        af11.z = fmaxf(af11.z, 0.f); af11.w = fmaxf(af11.w, 0.f);
        half8 bh[4], bl[4];
#pragma unroll
        for (int nt = 0; nt < 4; ++nt) {
            int off = (nt * 16 + l16) * 320 + k0 * 2 + quad * 16;
            bh[nt] = *(const half8*)(smem + off);
            bl[nt] = *(const half8*)(smem + 20480 + off);
        }
        half8 ah0, al0, ah1, al1;
        split8(af00, af01, ah0, al0);
        split8(af10, af11, ah1, al1);
#pragma unroll
        for (int nt = 0; nt < 4; ++nt) {
            acc[0][nt] = __builtin_amdgcn_mfma_f32_16x16x32_f16(ah0, bh[nt], acc[0][nt], 0, 0, 0);
            acc[1][nt] = __builtin_amdgcn_mfma_f32_16x16x32_f16(ah1, bh[nt], acc[1][nt], 0, 0, 0);
            acc[0][nt] = __builtin_amdgcn_mfma_f32_16x16x32_f16(ah0, bl[nt], acc[0][nt], 0, 0, 0);
            acc[1][nt] = __builtin_amdgcn_mfma_f32_16x16x32_f16(ah1, bl[nt], acc[1][nt], 0, 0, 0);
            acc[0][nt] = __builtin_amdgcn_mfma_f32_16x16x32_f16(al0, bh[nt], acc[0][nt], 0, 0, 0);
            acc[1][nt] = __builtin_amdgcn_mfma_f32_16x16x32_f16(al1, bh[nt], acc[1][nt], 0, 0, 0);
        }
    }

#pragma unroll
    for (int nt = 0; nt < 4; ++nt) {
        int col = nt * 16 + l16;
        float bv = bias[col];
#pragma unroll
        for (int mt = 0; mt < 2; ++mt)
#pragma unroll
            for (int r = 0; r < 4; ++r) {
                int row = m0 + mt * 16 + quad * 4 + r;
                if (row < M) out[(size_t)row * 64 + col] = acc[mt][nt][r] + bv;
            }
    }
}

// ---------------- GEMM3: relu([M,64]) @ [64,16] + bias ----------------

__global__ __launch_bounds__(256) void gemm3(const float* __restrict__ H,
                                             const float* __restrict__ W,
                                             const float* __restrict__ bias,
                                             float* __restrict__ out, int M) {
    __shared__ float Ws[64 * 16];
    __shared__ float Xs[32 * 68];
    int t = threadIdx.x;
    int m0 = blockIdx.x * 32;
    ((float4*)Ws)[t] = ((const float4*)W)[t];
#pragma unroll
    for (int i = 0; i < 2; i++) {
        int idx = t + i * 256;
        int gi = idx * 4;
        int row = gi >> 6, col = gi & 63;
        float4 v = make_float4(0.f, 0.f, 0.f, 0.f);
        if (m0 + row < M) v = *(const float4*)(H + (size_t)(m0 + row) * 64 + col);
        v.x = fmaxf(v.x, 0.f); v.y = fmaxf(v.y, 0.f);
        v.z = fmaxf(v.z, 0.f); v.w = fmaxf(v.w, 0.f);
        *(float4*)&Xs[row * 68 + col] = v;
    }
    __syncthreads();
    int node = t >> 3;
    int j = t & 7;
    float a0 = 0.f, a1 = 0.f;
#pragma unroll 8
    for (int k = 0; k < 64; ++k) {
        float xv = Xs[node * 68 + k];
        a0 += xv * Ws[k * 16 + j * 2];
        a1 += xv * Ws[k * 16 + j * 2 + 1];
    }
    int row = m0 + node;
    if (row < M) {
        a0 += bias[j * 2];
        a1 += bias[j * 2 + 1];
        float2 r = make_float2(a0, a1);
        *(float2*)(out + (size_t)row * 16 + j * 2) = r;
    }
}

// ---------------- CSR SpMM kernels (float4 gathers, 1KB/instr) ----------------

__global__ __launch_bounds__(256) void spmm128(const int* __restrict__ rowptr,
                                               const int2* __restrict__ ssv,
                                               const float* __restrict__ T,
                                               float* __restrict__ H, int N) {
    int lane = threadIdx.x & 63;
    int node = __builtin_amdgcn_readfirstlane(blockIdx.x * 4 + (threadIdx.x >> 6));
    if (node >= N) return;
    int beg = rowptr[node], end = rowptr[node + 1];
    int half = lane >> 5;
    int c4 = (lane & 31) << 2;            // column offset 0..124
    float4 acc = make_float4(0.f, 0.f, 0.f, 0.f);
    int i = beg;
    int cnt = end - beg;
    int n8 = beg + (cnt & ~7);
    for (; i < n8; i += 8) {
#pragma unroll
        for (int u = 0; u < 4; ++u) {
            int2 e = ssv[i + 2 * u + half];
            float v = __int_as_float(e.y);
            float4 xv = *(const float4*)(T + ((size_t)e.x << 7) + c4);
            acc.x += v * xv.x; acc.y += v * xv.y;
            acc.z += v * xv.z; acc.w += v * xv.w;
        }
    }
    int n2 = beg + (cnt & ~1);
    for (; i < n2; i += 2) {
        int2 e = ssv[i + half];
        float v = __int_as_float(e.y);
        float4 xv = *(const float4*)(T + ((size_t)e.x << 7) + c4);
        acc.x += v * xv.x; acc.y += v * xv.y;
        acc.z += v * xv.z; acc.w += v * xv.w;
    }
    if (i < end) {                        // single leftover: half 1 contributes 0
        int2 e = ssv[i];
        float v = half ? 0.f : __int_as_float(e.y);
        float4 xv = *(const float4*)(T + ((size_t)e.x << 7) + c4);
        acc.x += v * xv.x; acc.y += v * xv.y;
        acc.z += v * xv.z; acc.w += v * xv.w;
    }
    acc.x += __shfl_xor(acc.x, 32, 64);
    acc.y += __shfl_xor(acc.y, 32, 64);
    acc.z += __shfl_xor(acc.z, 32, 64);
    acc.w += __shfl_xor(acc.w, 32, 64);
    if (half == 0)
        *(float4*)(H + ((size_t)node << 7) + c4) = acc;
}

__global__ __launch_bounds__(256) void spmm64(const int* __restrict__ rowptr,
                                              const int2* __restrict__ ssv,
                                              const float* __restrict__ T,
                                              float* __restrict__ H, int N) {
    int lane = threadIdx.x & 63;
    int node = __builtin_amdgcn_readfirstlane(blockIdx.x * 4 + (threadIdx.x >> 6));
    if (node >= N) return;
    int beg = rowptr[node], end = rowptr[node + 1];
    int es = lane >> 4;                   // edge slot 0..3
    int c4 = (lane & 15) << 2;            // column offset 0..60
    float4 acc = make_float4(0.f, 0.f, 0.f, 0.f);
    int i = beg;
    int cnt = end - beg;
    int n8 = beg + (cnt & ~7);
    for (; i < n8; i += 8) {
#pragma unroll
        for (int u = 0; u < 2; ++u) {
            int2 e = ssv[i + 4 * u + es];
            float v = __int_as_float(e.y);
            float4 xv = *(const float4*)(T + ((size_t)e.x << 6) + c4);
            acc.x += v * xv.x; acc.y += v * xv.y;
            acc.z += v * xv.z; acc.w += v * xv.w;
        }
    }
    int n4 = beg + (cnt & ~3);
    for (; i < n4; i += 4) {
        int2 e = ssv[i + es];
        float v = __int_as_float(e.y);
        float4 xv = *(const float4*)(T + ((size_t)e.x << 6) + c4);
        acc.x += v * xv.x; acc.y += v * xv.y;
        acc.z += v * xv.z; acc.w += v * xv.w;
    }
    if (i < end) {                        // 1..3 leftover edges
        int idx = i + es;
        int2 e = ssv[idx < end ? idx : i];
        float v = (idx < end) ? __int_as_float(e.y) : 0.f;
        float4 xv = *(const float4*)(T + ((size_t)e.x << 6) + c4);
        acc.x += v * xv.x; acc.y += v * xv.y;
        acc.z += v * xv.z; acc.w += v * xv.w;
    }
    acc.x += __shfl_xor(acc.x, 16, 64);
    acc.y += __shfl_xor(acc.y, 16, 64);
    acc.z += __shfl_xor(acc.z, 16, 64);
    acc.w += __shfl_xor(acc.w, 16, 64);
    acc.x += __shfl_xor(acc.x, 32, 64);
    acc.y += __shfl_xor(acc.y, 32, 64);
    acc.z += __shfl_xor(acc.z, 32, 64);
    acc.w += __shfl_xor(acc.w, 32, 64);
    if (lane < 16)
        *(float4*)(H + ((size_t)node << 6) + c4) = acc;
}

__global__ __launch_bounds__(256) void spmm_argmax(const int* __restrict__ rowptr,
                                                   const int2* __restrict__ ssv,
                                                   const float* __restrict__ T,
                                                   int* __restrict__ out, int N) {
    int t = threadIdx.x;
    int node = blockIdx.x * 64 + (t >> 2);
    int q = t & 3;
    int c4 = q << 2;                      // class offset 0,4,8,12
    int beg = 0, end = 0;
    if (node < N) { beg = rowptr[node]; end = rowptr[node + 1]; }
    float4 acc = make_float4(0.f, 0.f, 0.f, 0.f);
    int i = beg;
    int cnt = end - beg;
    int n4 = beg + (cnt & ~3);
    for (; i < n4; i += 4) {
#pragma unroll
        for (int u = 0; u < 4; ++u) {
            int2 e = ssv[i + u];
            float v = __int_as_float(e.y);
            float4 xv = *(const float4*)(T + ((size_t)e.x << 4) + c4);
            acc.x += v * xv.x; acc.y += v * xv.y;
            acc.z += v * xv.z; acc.w += v * xv.w;
        }
    }
    for (; i < end; ++i) {
        int2 e = ssv[i];
        float v = __int_as_float(e.y);
        float4 xv = *(const float4*)(T + ((size_t)e.x << 4) + c4);
        acc.x += v * xv.x; acc.y += v * xv.y;
        acc.z += v * xv.z; acc.w += v * xv.w;
    }
    float bv = acc.x; int bi = c4;
    if (acc.y > bv) { bv = acc.y; bi = c4 + 1; }
    if (acc.z > bv) { bv = acc.z; bi = c4 + 2; }
    if (acc.w > bv) { bv = acc.w; bi = c4 + 3; }
#pragma unroll
    for (int off = 1; off <= 2; off <<= 1) {
        float ov = __shfl_xor(bv, off, 64);
        int oi = __shfl_xor(bi, off, 64);
        if (ov > bv || (ov == bv && oi < bi)) { bv = ov; bi = oi; }
    }
    if (node < N && q == 0) out[node] = bi;
}

// ---------------- launch ----------------

extern "C" void kernel_launch(void* const* d_in, const int* in_sizes, int n_in,
                              void* d_out, int out_size, void* d_ws, size_t ws_size,
                              hipStream_t stream) {
    const float* x  = (const float*)d_in[0];
    const int*   ei = (const int*)d_in[1];
    const float* ev = (const float*)d_in[2];
    const float* W1 = (const float*)d_in[3];
    const float* b1 = (const float*)d_in[4];
    const float* W2 = (const float*)d_in[5];
    const float* b2 = (const float*)d_in[6];
    const float* W3 = (const float*)d_in[7];
    const float* b3 = (const float*)d_in[8];
    int* out = (int*)d_out;

    int M = in_sizes[0] / 512;
    int E = in_sizes[2];
    const int* src = ei;
    const int* dst = ei + E;

    int NCH = (M + 1023) >> 10;              // scan chunks (<=128 for M<=131072)

    char* ws = (char*)d_ws;
    size_t off = 0;
    auto alloc = [&](size_t bytes) {
        size_t o = off;
        off += (bytes + 255) & ~(size_t)255;
        return o;
    };
    float*    tA      = (float*)(ws + alloc((size_t)M * 128 * 4));
    float*    hB      = (float*)(ws + alloc((size_t)M * 128 * 4));
    int2*     ssv     = (int2*) (ws + alloc((size_t)E * 8));
    int*      rowptr  = (int*)  (ws + alloc((size_t)(M + 1) * 4));
    int*      deg     = (int*)  (ws + alloc((size_t)M * 4));
    int*      cur     = (int*)  (ws + alloc((size_t)M * 4));
    int*      partial = (int*)  (ws + alloc(128 * 4));
    _Float16* w1hi    = (_Float16*)(ws + alloc(512 * 128 * 2));
    _Float16* w1lo    = (_Float16*)(ws + alloc(512 * 128 * 2));
    _Float16* w2hi    = (_Float16*)(ws + alloc(128 * 64 * 2));
    _Float16* w2lo    = (_Float16*)(ws + alloc(128 * 64 * 2));

    // ---- CSR build (direct node-level) + weight prep ----
    hipMemsetAsync(deg, 0, (size_t)M * 4, stream);
    int cntBlk = 288 + (E + 1023) / 1024;
    k_prep_count<<<cntBlk, 256, 0, stream>>>(W1, W2, w1hi, w1lo, w2hi, w2lo, dst, deg, E);
    k_scan_a<<<NCH, 1024, 0, stream>>>(deg, rowptr, partial, M);
    k_scan_b<<<NCH, 1024, 0, stream>>>(partial, rowptr, cur, M, E, NCH);
    k_scatter<<<(E + 1023) / 1024, 256, 0, stream>>>(src, dst, ev, cur, ssv, E);

    // ---- layer 1 ----
    gemm1_mfma<<<(M + 127) / 128, 256, 0, stream>>>(x, w1hi, w1lo, b1, tA, M);
    spmm128<<<(M + 3) / 4, 256, 0, stream>>>(rowptr, ssv, tA, hB, M);
    // ---- layer 2 (relu fused into gemm2 input) ----
    gemm2_mfma<<<(M + 127) / 128, 256, 0, stream>>>(hB, w2hi, w2lo, b2, tA, M);
    spmm64<<<(M + 3) / 4, 256, 0, stream>>>(rowptr, ssv, tA, hB, M);
    // ---- layer 3 + argmax ----
    gemm3<<<(M + 31) / 32, 256, 0, stream>>>(hB, W3, b3, tA, M);
    spmm_argmax<<<(M + 63) / 64, 256, 0, stream>>>(rowptr, ssv, tA, out, M);
}

// Round 3
// 643.950 us; speedup vs baseline: 1.1600x; 1.1600x over previous
//
#include <hip/hip_runtime.h>

typedef _Float16 half8 __attribute__((ext_vector_type(8)));
typedef float floatx4 __attribute__((ext_vector_type(4)));

#define BSHIFT 7              // 128 nodes per bucket
#define BMASK 127
#define EPB 8192              // edges per pass-1 block
#define P2CAP 4096            // LDS edge stash per bucket (mean ~2046, 45 sigma)

// global -> LDS async copy, 16B per lane.
__device__ __forceinline__ void g2lds16(const void* g, void* l) {
    __builtin_amdgcn_global_load_lds(
        (const __attribute__((address_space(1))) void*)(unsigned long long)g,
        (__attribute__((address_space(3))) void*)(unsigned int)(unsigned long long)l,
        16, 0, 0);
}

// ---------------- CSR build: two-level counting sort, LDS atomics only ----------------
// K1: fused weight-prep (blocks 0..287) + per-block dst-bucket histogram (blocks 288+)
__global__ __launch_bounds__(256) void k1_prep_hist(const float* __restrict__ W1,
                                                    const float* __restrict__ W2,
                                                    _Float16* __restrict__ w1hi,
                                                    _Float16* __restrict__ w1lo,
                                                    _Float16* __restrict__ w2hi,
                                                    _Float16* __restrict__ w2lo,
                                                    const int* __restrict__ dst,
                                                    int* __restrict__ hist,
                                                    int E, int NBUCK) {
    __shared__ int lh[1024];
    int b = blockIdx.x, t = threadIdx.x;
    if (b < 256) {            // prep W1: fp32 -> fp16 hi/lo, transposed [n][k]
        int tid = b * 256 + t;            // 65536 = 128*512
        int n = tid >> 9;
        int k = tid & 511;
        float w = W1[(size_t)k * 128 + n];
        _Float16 h = (_Float16)w;
        w1hi[tid] = h;
        w1lo[tid] = (_Float16)(w - (float)h);
        return;
    }
    if (b < 288) {            // prep W2
        int tid = (b - 256) * 256 + t;    // 8192 = 64*128
        int n = tid >> 7;
        int k = tid & 127;
        float w = W2[(size_t)k * 64 + n];
        _Float16 h = (_Float16)w;
        w2hi[tid] = h;
        w2lo[tid] = (_Float16)(w - (float)h);
        return;
    }
    int bb = b - 288;
    for (int k = t; k < NBUCK; k += 256) lh[k] = 0;
    __syncthreads();
    int e0 = bb * EPB;
    int eend = min(e0 + EPB, E);
    for (int i = e0 + t; i < eend; i += 256)
        atomicAdd(&lh[dst[i] >> BSHIFT], 1);
    __syncthreads();
    for (int k = t; k < NBUCK; k += 256) hist[(size_t)bb * NBUCK + k] = lh[k];
}

// K2: per-bucket parallel scan over blocks (one workgroup per bucket; no bubble)
__global__ __launch_bounds__(256) void k2_scanA(const int* __restrict__ hist,
                                                int* __restrict__ blockOff,
                                                int* __restrict__ btot,
                                                int NBLK, int NBUCK) {
    __shared__ int s[256];
    int k = blockIdx.x;       // bucket
    int t = threadIdx.x;
    int carry = 0;
    for (int base = 0; base < NBLK; base += 256) {
        int b = base + t;
        int c = (b < NBLK) ? hist[(size_t)b * NBUCK + k] : 0;
        s[t] = c;
        __syncthreads();
        for (int off = 1; off < 256; off <<= 1) {
            int v = (t >= off) ? s[t - off] : 0;
            __syncthreads();
            s[t] += v;
            __syncthreads();
        }
        if (b < NBLK) blockOff[(size_t)b * NBUCK + k] = carry + s[t] - c;
        carry += s[255];
        __syncthreads();
    }
    if (t == 0) btot[k] = carry;
}

// K2b: exclusive scan of bucket totals (NBUCK <= 1024)
__global__ __launch_bounds__(1024) void k2b_bscan(const int* __restrict__ btot,
                                                  int* __restrict__ bstart,
                                                  int* __restrict__ rowptr,
                                                  int NBUCK, int M, int E) {
    __shared__ int s[1024];
    int tid = threadIdx.x;
    int v = (tid < NBUCK) ? btot[tid] : 0;
    s[tid] = v;
    __syncthreads();
    for (int off = 1; off < 1024; off <<= 1) {
        int t = (tid >= off) ? s[tid - off] : 0;
        __syncthreads();
        s[tid] += t;
        __syncthreads();
    }
    if (tid < NBUCK) bstart[tid] = s[tid] - v;
    if (tid == 0) rowptr[M] = E;
}

// ---------------- role bodies for fused kernels ----------------

__device__ __forceinline__ void p1d_body(int b, const int* __restrict__ src,
                                         const int* __restrict__ dst,
                                         const float* __restrict__ val,
                                         const int* __restrict__ bstart,
                                         const int* __restrict__ blockOff,
                                         int2* __restrict__ tmp,
                                         int E, int NBUCK, int* cur) {
    int t = threadIdx.x;
    for (int k = t; k < NBUCK; k += 256)
        cur[k] = bstart[k] + blockOff[(size_t)b * NBUCK + k];
    __syncthreads();
    int e0 = b * EPB;
    int eend = min(e0 + EPB, E);
    for (int i = e0 + t; i < eend; i += 256) {
        int d = dst[i];
        int p = atomicAdd(&cur[d >> BSHIFT], 1);
        int2 pk;
        pk.x = src[i] | ((d & BMASK) << 20);   // src < 2^20
        pk.y = __float_as_int(val[i]);
        tmp[p] = pk;
    }
}

__device__ __forceinline__ void p2_body(int k, const int2* __restrict__ tmp,
                                        const int* __restrict__ bstart,
                                        const int* __restrict__ btot,
                                        int* __restrict__ rowptr,
                                        int2* __restrict__ ssv, int M, char* lds) {
    int2* ebuf = (int2*)lds;               // 32768 B
    int* h    = (int*)(lds + 32768);       // 512 B
    int* sc   = (int*)(lds + 33280);
    int* curs = (int*)(lds + 33792);
    int t = threadIdx.x;
    int base = bstart[k], n = btot[k];
    for (int j = t; j < 128; j += 256) h[j] = 0;
    __syncthreads();
    int nl = min(n, P2CAP);
    for (int i = t; i < nl; i += 256) {
        int2 e = tmp[base + i];
        ebuf[i] = e;
        atomicAdd(&h[e.x >> 20], 1);
    }
    for (int i = P2CAP + t; i < n; i += 256) {   // overflow: never in practice
        int2 e = tmp[base + i];
        atomicAdd(&h[e.x >> 20], 1);
    }
    __syncthreads();
    if (t < 128) sc[t] = h[t];
    __syncthreads();
    for (int off = 1; off < 128; off <<= 1) {
        int v = (t < 128 && t >= off) ? sc[t - off] : 0;
        __syncthreads();
        if (t < 128) sc[t] += v;
        __syncthreads();
    }
    if (t < 128) {
        int node = (k << BSHIFT) + t;
        int excl = sc[t] - h[t];
        if (node < M) rowptr[node] = base + excl;
        curs[t] = excl;
    }
    __syncthreads();
    for (int i = t; i < nl; i += 256) {
        int2 e = ebuf[i];
        int p = atomicAdd(&curs[e.x >> 20], 1);
        int2 o; o.x = e.x & 0xFFFFF; o.y = e.y;
        ssv[base + p] = o;
    }
    for (int i = P2CAP + t; i < n; i += 256) {
        int2 e = tmp[base + i];
        int p = atomicAdd(&curs[e.x >> 20], 1);
        int2 o; o.x = e.x & 0xFFFFF; o.y = e.y;
        ssv[base + p] = o;
    }
}

// ---------------- split helper ----------------

__device__ __forceinline__ void split8(float4 f0, float4 f1, half8& h, half8& l) {
    float f[8] = {f0.x, f0.y, f0.z, f0.w, f1.x, f1.y, f1.z, f1.w};
#pragma unroll
    for (int j = 0; j < 8; ++j) {
        _Float16 hi = (_Float16)f[j];
        h[j] = hi;
        l[j] = (_Float16)(f[j] - (float)hi);
    }
}

// ---------------- GEMM1 body: [128 rows @ bm, 512]@[512,128]+b1, split-fp16 MFMA ----

__device__ __forceinline__ void gemm1_body(int bm, char* smem,
                                           const float* __restrict__ X,
                                           const _Float16* __restrict__ Whi,
                                           const _Float16* __restrict__ Wlo,
                                           const float* __restrict__ bias,
                                           float* __restrict__ out, int M) {
    int t = threadIdx.x;
    int w = t >> 6;
    int lane = t & 63;
    int quad = lane >> 4;
    int l16 = lane & 15;
    int m0 = bm + w * 32;

    int ra0 = min(m0 + l16, M - 1);
    int ra1 = min(m0 + 16 + l16, M - 1);
    const float* a0p = X + (size_t)ra0 * 512 + quad * 8;
    const float* a1p = X + (size_t)ra1 * 512 + quad * 8;

    int chunk0 = w * 4;
    const _Float16* gsrc[4];
#pragma unroll
    for (int c = 0; c < 4; ++c) {
        int idx = (chunk0 + c) * 1024 + lane * 16;
        int sec = idx >> 13;
        int row = (idx & 8191) >> 6;
        int kch = (idx >> 4) & 3;
        gsrc[c] = (sec ? Wlo : Whi) + (size_t)row * 512 + kch * 8;
    }
#pragma unroll
    for (int c = 0; c < 4; ++c)
        g2lds16(gsrc[c], smem + (chunk0 + c) * 1024);
    float4 af00 = *(const float4*)(a0p);
    float4 af01 = *(const float4*)(a0p + 4);
    float4 af10 = *(const float4*)(a1p);
    float4 af11 = *(const float4*)(a1p + 4);

    floatx4 acc[2][8];
#pragma unroll
    for (int mt = 0; mt < 2; ++mt)
#pragma unroll
        for (int nt = 0; nt < 8; ++nt) acc[mt][nt] = (floatx4){0.f, 0.f, 0.f, 0.f};

    for (int i = 0; i < 16; ++i) {
        int k0 = i * 32;
        __syncthreads();
        if (i < 15) {
            char* nbuf = smem + ((i + 1) & 1) * 16384;
#pragma unroll
            for (int c = 0; c < 4; ++c)
                g2lds16(gsrc[c] + k0 + 32, nbuf + (chunk0 + c) * 1024);
        }
        float4 nf00 = af00, nf01 = af01, nf10 = af10, nf11 = af11;
        if (i < 15) {
            nf00 = *(const float4*)(a0p + k0 + 32);
            nf01 = *(const float4*)(a0p + k0 + 36);
            nf10 = *(const float4*)(a1p + k0 + 32);
            nf11 = *(const float4*)(a1p + k0 + 36);
        }
        const char* buf = smem + (i & 1) * 16384;
        half8 bh[8], bl[8];
#pragma unroll
        for (int nt = 0; nt < 8; ++nt) {
            int off = (nt * 16 + l16) * 64 + quad * 16;
            bh[nt] = *(const half8*)(buf + off);
            bl[nt] = *(const half8*)(buf + 8192 + off);
        }
        half8 ah0, al0, ah1, al1;
        split8(af00, af01, ah0, al0);
        split8(af10, af11, ah1, al1);
#pragma unroll
        for (int nt = 0; nt < 8; ++nt) {
            acc[0][nt] = __builtin_amdgcn_mfma_f32_16x16x32_f16(ah0, bh[nt], acc[0][nt], 0, 0, 0);
            acc[1][nt] = __builtin_amdgcn_mfma_f32_16x16x32_f16(ah1, bh[nt], acc[1][nt], 0, 0, 0);
            acc[0][nt] = __builtin_amdgcn_mfma_f32_16x16x32_f16(ah0, bl[nt], acc[0][nt], 0, 0, 0);
            acc[1][nt] = __builtin_amdgcn_mfma_f32_16x16x32_f16(ah1, bl[nt], acc[1][nt], 0, 0, 0);
            acc[0][nt] = __builtin_amdgcn_mfma_f32_16x16x32_f16(al0, bh[nt], acc[0][nt], 0, 0, 0);
            acc[1][nt] = __builtin_amdgcn_mfma_f32_16x16x32_f16(al1, bh[nt], acc[1][nt], 0, 0, 0);
        }
        af00 = nf00; af01 = nf01; af10 = nf10; af11 = nf11;
    }

#pragma unroll
    for (int nt = 0; nt < 8; ++nt) {
        int col = nt * 16 + l16;
        float bv = bias[col];
#pragma unroll
        for (int mt = 0; mt < 2; ++mt)
#pragma unroll
            for (int r = 0; r < 4; ++r) {
                int row = m0 + mt * 16 + quad * 4 + r;
                if (row < M) out[(size_t)row * 128 + col] = acc[mt][nt][r] + bv;
            }
    }
}

// K3: p1d scatter (blocks 0..NBLK-1) fused with gemm1 first half
__global__ __launch_bounds__(256) void k3_p1d_gemm1a(const int* __restrict__ src,
                                                     const int* __restrict__ dst,
                                                     const float* __restrict__ val,
                                                     const int* __restrict__ bstart,
                                                     const int* __restrict__ blockOff,
                                                     int2* __restrict__ tmp,
                                                     int E, int NBUCK, int NBLK,
                                                     const float* __restrict__ X,
                                                     const _Float16* __restrict__ Whi,
                                                     const _Float16* __restrict__ Wlo,
                                                     const float* __restrict__ bias,
                                                     float* __restrict__ out, int M) {
    __shared__ __align__(16) char lds[32768];
    int b = blockIdx.x;
    if (b < NBLK) {
        p1d_body(b, src, dst, val, bstart, blockOff, tmp, E, NBUCK, (int*)lds);
        return;
    }
    gemm1_body((b - NBLK) * 128, lds, X, Whi, Wlo, bias, out, M);
}

// K4: p2 sort (blocks 0..NBUCK-1) fused with gemm1 second half
__global__ __launch_bounds__(256) void k4_p2_gemm1b(const int2* __restrict__ tmp,
                                                    const int* __restrict__ bstart,
                                                    const int* __restrict__ btot,
                                                    int* __restrict__ rowptr,
                                                    int2* __restrict__ ssv,
                                                    int M, int NBUCK, int g1a,
                                                    const float* __restrict__ X,
                                                    const _Float16* __restrict__ Whi,
                                                    const _Float16* __restrict__ Wlo,
                                                    const float* __restrict__ bias,
                                                    float* __restrict__ out) {
    __shared__ __align__(16) char lds[34304];
    int b = blockIdx.x;
    if (b < NBUCK) {
        p2_body(b, tmp, bstart, btot, rowptr, ssv, M, lds);
        return;
    }
    gemm1_body((g1a + b - NBUCK) * 128, lds, X, Whi, Wlo, bias, out, M);
}

// ---------------- GEMM2: relu([M,128])@[128,64]+b2, split-fp16 MFMA ----------------

__global__ __launch_bounds__(256) void gemm2_mfma(const float* __restrict__ H,
                                                  const _Float16* __restrict__ Whi,
                                                  const _Float16* __restrict__ Wlo,
                                                  const float* __restrict__ bias,
                                                  float* __restrict__ out, int M) {
    __shared__ char smem[2 * 64 * 320];
    int t = threadIdx.x;
#pragma unroll
    for (int i = 0; i < 4; ++i) {
        int gidx = i * 256 + t;
        int row = gidx >> 4, col = gidx & 15;
        *(float4*)(smem + row * 320 + col * 16) = ((const float4*)Whi)[gidx];
        *(float4*)(smem + 20480 + row * 320 + col * 16) = ((const float4*)Wlo)[gidx];
    }
    __syncthreads();

    int w = t >> 6;
    int lane = t & 63;
    int quad = lane >> 4;
    int l16 = lane & 15;
    int m0 = blockIdx.x * 128 + w * 32;
    int ra0 = min(m0 + l16, M - 1);
    int ra1 = min(m0 + 16 + l16, M - 1);
    const float* a0p = H + (size_t)ra0 * 128 + quad * 8;
    const float* a1p = H + (size_t)ra1 * 128 + quad * 8;

    floatx4 acc[2][4];
#pragma unroll
    for (int mt = 0; mt < 2; ++mt)
#pragma unroll
        for (int nt = 0; nt < 4; ++nt) acc[mt][nt] = (floatx4){0.f, 0.f, 0.f, 0.f};

#pragma unroll
    for (int k0 = 0; k0 < 128; k0 += 32) {
        float4 af00 = *(const float4*)(a0p + k0);
        float4 af01 = *(const float4*)(a0p + k0 + 4);
        float4 af10 = *(const float4*)(a1p + k0);
        float4 af11 = *(const float4*)(a1p + k0 + 4);
        af00.x = fmaxf(af00.x, 0.f); af00.y = fmaxf(af00.y, 0.f);
        af00.z = fmaxf(af00.z, 0.f); af00.w = fmaxf(af00.w, 0.f);
        af01.x = fmaxf(af01.x, 0.f); af01.y = fmaxf(af01.y, 0.f);
        af01.z = fmaxf(af01.z, 0.f); af01.w = fmaxf(af01.w, 0.f);
        af10.x = fmaxf(af10.x, 0.f); af10.y = fmaxf(af10.y, 0.f);
        af10.z = fmaxf(af10.z, 0.f); af10.w = fmaxf(af10.w, 0.f);
        af11.x = fmaxf(af11.x, 0.f); af11.y = fmaxf(af11.y, 0.f);
        af11.z = fmaxf(af11.z, 0.f); af11.w = fmaxf(af11.w, 0.f);
        half8 bh[4], bl[4];
#pragma unroll
        for (int nt = 0; nt < 4; ++nt) {
            int off = (nt * 16 + l16) * 320 + k0 * 2 + quad * 16;
            bh[nt] = *(const half8*)(smem + off);
            bl[nt] = *(const half8*)(smem + 20480 + off);
        }
        half8 ah0, al0, ah1, al1;
        split8(af00, af01, ah0, al0);
        split8(af10, af11, ah1, al1);
#pragma unroll
        for (int nt = 0; nt < 4; ++nt) {
            acc[0][nt] = __builtin_amdgcn_mfma_f32_16x16x32_f16(ah0, bh[nt], acc[0][nt], 0, 0, 0);
            acc[1][nt] = __builtin_amdgcn_mfma_f32_16x16x32_f16(ah1, bh[nt], acc[1][nt], 0, 0, 0);
            acc[0][nt] = __builtin_amdgcn_mfma_f32_16x16x32_f16(ah0, bl[nt], acc[0][nt], 0, 0, 0);
            acc[1][nt] = __builtin_amdgcn_mfma_f32_16x16x32_f16(ah1, bl[nt], acc[1][nt], 0, 0, 0);
            acc[0][nt] = __builtin_amdgcn_mfma_f32_16x16x32_f16(al0, bh[nt], acc[0][nt], 0, 0, 0);
            acc[1][nt] = __builtin_amdgcn_mfma_f32_16x16x32_f16(al1, bh[nt], acc[1][nt], 0, 0, 0);
        }
    }

#pragma unroll
    for (int nt = 0; nt < 4; ++nt) {
        int col = nt * 16 + l16;
        float bv = bias[col];
#pragma unroll
        for (int mt = 0; mt < 2; ++mt)
#pragma unroll
            for (int r = 0; r < 4; ++r) {
                int row = m0 + mt * 16 + quad * 4 + r;
                if (row < M) out[(size_t)row * 64 + col] = acc[mt][nt][r] + bv;
            }
    }
}

// ---------------- GEMM3: relu([M,64]) @ [64,16] + bias ----------------

__global__ __launch_bounds__(256) void gemm3(const float* __restrict__ H,
                                             const float* __restrict__ W,
                                             const float* __restrict__ bias,
                                             float* __restrict__ out, int M) {
    __shared__ float Ws[64 * 16];
    __shared__ float Xs[32 * 68];
    int t = threadIdx.x;
    int m0 = blockIdx.x * 32;
    ((float4*)Ws)[t] = ((const float4*)W)[t];
#pragma unroll
    for (int i = 0; i < 2; i++) {
        int idx = t + i * 256;
        int gi = idx * 4;
        int row = gi >> 6, col = gi & 63;
        float4 v = make_float4(0.f, 0.f, 0.f, 0.f);
        if (m0 + row < M) v = *(const float4*)(H + (size_t)(m0 + row) * 64 + col);
        v.x = fmaxf(v.x, 0.f); v.y = fmaxf(v.y, 0.f);
        v.z = fmaxf(v.z, 0.f); v.w = fmaxf(v.w, 0.f);
        *(float4*)&Xs[row * 68 + col] = v;
    }
    __syncthreads();
    int node = t >> 3;
    int j = t & 7;
    float a0 = 0.f, a1 = 0.f;
#pragma unroll 8
    for (int k = 0; k < 64; ++k) {
        float xv = Xs[node * 68 + k];
        a0 += xv * Ws[k * 16 + j * 2];
        a1 += xv * Ws[k * 16 + j * 2 + 1];
    }
    int row = m0 + node;
    if (row < M) {
        a0 += bias[j * 2];
        a1 += bias[j * 2 + 1];
        float2 r = make_float2(a0, a1);
        *(float2*)(out + (size_t)row * 16 + j * 2) = r;
    }
}

// ---------------- CSR SpMM kernels (float4 gathers, 1KB/instr) ----------------

__global__ __launch_bounds__(256) void spmm128(const int* __restrict__ rowptr,
                                               const int2* __restrict__ ssv,
                                               const float* __restrict__ T,
                                               float* __restrict__ H, int N) {
    int lane = threadIdx.x & 63;
    int node = __builtin_amdgcn_readfirstlane(blockIdx.x * 4 + (threadIdx.x >> 6));
    if (node >= N) return;
    int beg = rowptr[node], end = rowptr[node + 1];
    int half = lane >> 5;
    int c4 = (lane & 31) << 2;            // column offset 0..124
    float4 acc = make_float4(0.f, 0.f, 0.f, 0.f);
    int i = beg;
    int cnt = end - beg;
    int n8 = beg + (cnt & ~7);
    for (; i < n8; i += 8) {
#pragma unroll
        for (int u = 0; u < 4; ++u) {
            int2 e = ssv[i + 2 * u + half];
            float v = __int_as_float(e.y);
            float4 xv = *(const float4*)(T + ((size_t)e.x << 7) + c4);
            acc.x += v * xv.x; acc.y += v * xv.y;
            acc.z += v * xv.z; acc.w += v * xv.w;
        }
    }
    int n2 = beg + (cnt & ~1);
    for (; i < n2; i += 2) {
        int2 e = ssv[i + half];
        float v = __int_as_float(e.y);
        float4 xv = *(const float4*)(T + ((size_t)e.x << 7) + c4);
        acc.x += v * xv.x; acc.y += v * xv.y;
        acc.z += v * xv.z; acc.w += v * xv.w;
    }
    if (i < end) {                        // single leftover: half 1 contributes 0
        int2 e = ssv[i];
        float v = half ? 0.f : __int_as_float(e.y);
        float4 xv = *(const float4*)(T + ((size_t)e.x << 7) + c4);
        acc.x += v * xv.x; acc.y += v * xv.y;
        acc.z += v * xv.z; acc.w += v * xv.w;
    }
    acc.x += __shfl_xor(acc.x, 32, 64);
    acc.y += __shfl_xor(acc.y, 32, 64);
    acc.z += __shfl_xor(acc.z, 32, 64);
    acc.w += __shfl_xor(acc.w, 32, 64);
    if (half == 0)
        *(float4*)(H + ((size_t)node << 7) + c4) = acc;
}

__global__ __launch_bounds__(256) void spmm64(const int* __restrict__ rowptr,
                                              const int2* __restrict__ ssv,
                                              const float* __restrict__ T,
                                              float* __restrict__ H, int N) {
    int lane = threadIdx.x & 63;
    int node = __builtin_amdgcn_readfirstlane(blockIdx.x * 4 + (threadIdx.x >> 6));
    if (node >= N) return;
    int beg = rowptr[node], end = rowptr[node + 1];
    int es = lane >> 4;                   // edge slot 0..3
    int c4 = (lane & 15) << 2;            // column offset 0..60
    float4 acc = make_float4(0.f, 0.f, 0.f, 0.f);
    int i = beg;
    int cnt = end - beg;
    int n8 = beg + (cnt & ~7);
    for (; i < n8; i += 8) {
#pragma unroll
        for (int u = 0; u < 2; ++u) {
            int2 e = ssv[i + 4 * u + es];
            float v = __int_as_float(e.y);
            float4 xv = *(const float4*)(T + ((size_t)e.x << 6) + c4);
            acc.x += v * xv.x; acc.y += v * xv.y;
            acc.z += v * xv.z; acc.w += v * xv.w;
        }
    }
    int n4 = beg + (cnt & ~3);
    for (; i < n4; i += 4) {
        int2 e = ssv[i + es];
        float v = __int_as_float(e.y);
        float4 xv = *(const float4*)(T + ((size_t)e.x << 6) + c4);
        acc.x += v * xv.x; acc.y += v * xv.y;
        acc.z += v * xv.z; acc.w += v * xv.w;
    }
    if (i < end) {                        // 1..3 leftover edges
        int idx = i + es;
        int2 e = ssv[idx < end ? idx : i];
        float v = (idx < end) ? __int_as_float(e.y) : 0.f;
        float4 xv = *(const float4*)(T + ((size_t)e.x << 6) + c4);
        acc.x += v * xv.x; acc.y += v * xv.y;
        acc.z += v * xv.z; acc.w += v * xv.w;
    }
    acc.x += __shfl_xor(acc.x, 16, 64);
    acc.y += __shfl_xor(acc.y, 16, 64);
    acc.z += __shfl_xor(acc.z, 16, 64);
    acc.w += __shfl_xor(acc.w, 16, 64);
    acc.x += __shfl_xor(acc.x, 32, 64);
    acc.y += __shfl_xor(acc.y, 32, 64);
    acc.z += __shfl_xor(acc.z, 32, 64);
    acc.w += __shfl_xor(acc.w, 32, 64);
    if (lane < 16)
        *(float4*)(H + ((size_t)node << 6) + c4) = acc;
}

__global__ __launch_bounds__(256) void spmm_argmax(const int* __restrict__ rowptr,
                                                   const int2* __restrict__ ssv,
                                                   const float* __restrict__ T,
                                                   int* __restrict__ out, int N) {
    int t = threadIdx.x;
    int node = blockIdx.x * 64 + (t >> 2);
    int q = t & 3;
    int c4 = q << 2;                      // class offset 0,4,8,12
    int beg = 0, end = 0;
    if (node < N) { beg = rowptr[node]; end = rowptr[node + 1]; }
    float4 acc = make_float4(0.f, 0.f, 0.f, 0.f);
    int i = beg;
    int cnt = end - beg;
    int n4 = beg + (cnt & ~3);
    for (; i < n4; i += 4) {
#pragma unroll
        for (int u = 0; u < 4; ++u) {
            int2 e = ssv[i + u];
            float v = __int_as_float(e.y);
            float4 xv = *(const float4*)(T + ((size_t)e.x << 4) + c4);
            acc.x += v * xv.x; acc.y += v * xv.y;
            acc.z += v * xv.z; acc.w += v * xv.w;
        }
    }
    for (; i < end; ++i) {
        int2 e = ssv[i];
        float v = __int_as_float(e.y);
        float4 xv = *(const float4*)(T + ((size_t)e.x << 4) + c4);
        acc.x += v * xv.x; acc.y += v * xv.y;
        acc.z += v * xv.z; acc.w += v * xv.w;
    }
    float bv = acc.x; int bi = c4;
    if (acc.y > bv) { bv = acc.y; bi = c4 + 1; }
    if (acc.z > bv) { bv = acc.z; bi = c4 + 2; }
    if (acc.w > bv) { bv = acc.w; bi = c4 + 3; }
#pragma unroll
    for (int off = 1; off <= 2; off <<= 1) {
        float ov = __shfl_xor(bv, off, 64);
        int oi = __shfl_xor(bi, off, 64);
        if (ov > bv || (ov == bv && oi < bi)) { bv = ov; bi = oi; }
    }
    if (node < N && q == 0) out[node] = bi;
}

// ---------------- launch ----------------

extern "C" void kernel_launch(void* const* d_in, const int* in_sizes, int n_in,
                              void* d_out, int out_size, void* d_ws, size_t ws_size,
                              hipStream_t stream) {
    const float* x  = (const float*)d_in[0];
    const int*   ei = (const int*)d_in[1];
    const float* ev = (const float*)d_in[2];
    const float* W1 = (const float*)d_in[3];
    const float* b1 = (const float*)d_in[4];
    const float* W2 = (const float*)d_in[5];
    const float* b2 = (const float*)d_in[6];
    const float* W3 = (const float*)d_in[7];
    const float* b3 = (const float*)d_in[8];
    int* out = (int*)d_out;

    int M = in_sizes[0] / 512;
    int E = in_sizes[2];
    const int* src = ei;
    const int* dst = ei + E;

    int NBUCK = (M + BMASK) >> BSHIFT;        // 782 for M=100k (<=1024 required)
    int NBLK  = (E + EPB - 1) / EPB;          // 196 for E=1.6M

    char* ws = (char*)d_ws;
    size_t off = 0;
    auto alloc = [&](size_t bytes) {
        size_t o = off;
        off += (bytes + 255) & ~(size_t)255;
        return o;
    };
    float*    tA      = (float*)(ws + alloc((size_t)M * 128 * 4));
    float*    hB      = (float*)(ws + alloc((size_t)M * 128 * 4));
    int2*     ssv     = (int2*) (ws + alloc((size_t)E * 8));
    int*      rowptr  = (int*)  (ws + alloc((size_t)(M + 1) * 4));
    int*      hist    = (int*)  (ws + alloc((size_t)NBLK * NBUCK * 4));
    int*      blockOff= (int*)  (ws + alloc((size_t)NBLK * NBUCK * 4));
    int*      btot    = (int*)  (ws + alloc((size_t)NBUCK * 4));
    int*      bstart  = (int*)  (ws + alloc((size_t)NBUCK * 4));
    _Float16* w1hi    = (_Float16*)(ws + alloc(512 * 128 * 2));
    _Float16* w1lo    = (_Float16*)(ws + alloc(512 * 128 * 2));
    _Float16* w2hi    = (_Float16*)(ws + alloc(128 * 64 * 2));
    _Float16* w2lo    = (_Float16*)(ws + alloc(128 * 64 * 2));
    int2*     tmp     = (int2*)hB;   // pass-1 staging overlays hB (free before SpMM)

    int G1  = (M + 127) / 128;       // gemm1 tile-blocks (782)
    int G1a = G1 / 2;                // first half (fused with p1d)
    int G1b = G1 - G1a;              // second half (fused with p2)

    // ---- build + weight prep + layer-1 GEMM, overlapped ----
    k1_prep_hist<<<288 + NBLK, 256, 0, stream>>>(W1, W2, w1hi, w1lo, w2hi, w2lo,
                                                 dst, hist, E, NBUCK);
    k2_scanA<<<NBUCK, 256, 0, stream>>>(hist, blockOff, btot, NBLK, NBUCK);
    k2b_bscan<<<1, 1024, 0, stream>>>(btot, bstart, rowptr, NBUCK, M, E);
    k3_p1d_gemm1a<<<NBLK + G1a, 256, 0, stream>>>(src, dst, ev, bstart, blockOff, tmp,
                                                  E, NBUCK, NBLK,
                                                  x, w1hi, w1lo, b1, tA, M);
    k4_p2_gemm1b<<<NBUCK + G1b, 256, 0, stream>>>(tmp, bstart, btot, rowptr, ssv,
                                                  M, NBUCK, G1a,
                                                  x, w1hi, w1lo, b1, tA);

    // ---- layer 1 aggregate ----
    spmm128<<<(M + 3) / 4, 256, 0, stream>>>(rowptr, ssv, tA, hB, M);
    // ---- layer 2 (relu fused into gemm2 input) ----
    gemm2_mfma<<<(M + 127) / 128, 256, 0, stream>>>(hB, w2hi, w2lo, b2, tA, M);
    spmm64<<<(M + 3) / 4, 256, 0, stream>>>(rowptr, ssv, tA, hB, M);
    // ---- layer 3 + argmax ----
    gemm3<<<(M + 31) / 32, 256, 0, stream>>>(hB, W3, b3, tA, M);
    spmm_argmax<<<(M + 63) / 64, 256, 0, stream>>>(rowptr, ssv, tA, out, M);
}